// Round 8
// baseline (475.029 us; speedup 1.0000x reference)
//
#include <hip/hip_runtime.h>
#include <hip/hip_bf16.h>
#include <math.h>

#define EMB 768
#define HEADS 12
#define DKH 64
#define DFF 3072
#define NB 16
#define SEQ 577
#define MTOK (NB*SEQ)      // 9232
#define BHN (NB*HEADS)     // 192
#define VLD 640            // vT row stride (bf16 elems)

typedef __attribute__((ext_vector_type(8))) short short8;
typedef __attribute__((ext_vector_type(4))) float f32x4;

__device__ __forceinline__ unsigned short f2bf(float f) {
  __hip_bfloat16 h = __float2bfloat16(f);
  return *reinterpret_cast<unsigned short*>(&h);
}

// fast GELU: x * sigmoid(2*0.79788456*(x + 0.044715 x^3)); |err| < ~1.5e-3
__device__ __forceinline__ float gelu_f(float x) {
  float u = x * (1.5957691216f + 0.0713548162726f * x * x);
  return x / (1.0f + __expf(-u));
}

__device__ __forceinline__ void gld_lds16(const unsigned short* g, unsigned short* l) {
  __builtin_amdgcn_global_load_lds(
      (const __attribute__((address_space(1))) unsigned int*)(g),
      (__attribute__((address_space(3))) unsigned int*)(l), 16, 0, 0);
}

template<int N> __device__ __forceinline__ void waitcnt_vm() {
  if constexpr (N == 0) asm volatile("s_waitcnt vmcnt(0)" ::: "memory");
  else if constexpr (N == 1) asm volatile("s_waitcnt vmcnt(1)" ::: "memory");
  else if constexpr (N == 2) asm volatile("s_waitcnt vmcnt(2)" ::: "memory");
  else if constexpr (N == 3) asm volatile("s_waitcnt vmcnt(3)" ::: "memory");
  else if constexpr (N == 4) asm volatile("s_waitcnt vmcnt(4)" ::: "memory");
  else if constexpr (N == 5) asm volatile("s_waitcnt vmcnt(5)" ::: "memory");
  else if constexpr (N == 6) asm volatile("s_waitcnt vmcnt(6)" ::: "memory");
  else if constexpr (N == 8) asm volatile("s_waitcnt vmcnt(8)" ::: "memory");
}

// ---------------- LayerNorm: fp32 [row,768] -> bf16 [row,768] ----------------
__global__ __launch_bounds__(256) void ln_kernel(
    const float* __restrict__ x, const float* __restrict__ g,
    const float* __restrict__ b, unsigned short* __restrict__ out) {
  int row = blockIdx.x;
  int tid = threadIdx.x;
  const float* xr = x + (long)row * EMB;
  float v0 = xr[tid], v1 = xr[tid + 256], v2 = xr[tid + 512];
  float s = v0 + v1 + v2;
  float sq = v0*v0 + v1*v1 + v2*v2;
  for (int off = 32; off; off >>= 1) {
    s  += __shfl_down(s,  off, 64);
    sq += __shfl_down(sq, off, 64);
  }
  __shared__ float sh[8];
  int wid = tid >> 6, lane = tid & 63;
  if (lane == 0) { sh[wid] = s; sh[4 + wid] = sq; }
  __syncthreads();
  s  = sh[0] + sh[1] + sh[2] + sh[3];
  sq = sh[4] + sh[5] + sh[6] + sh[7];
  float mu = s * (1.0f / EMB);
  float var = sq * (1.0f / EMB) - mu * mu;
  float rs = rsqrtf(var + 1e-5f);
  unsigned short* orow = out + (long)row * EMB;
  orow[tid]       = f2bf((v0 - mu) * rs * g[tid]       + b[tid]);
  orow[tid + 256] = f2bf((v1 - mu) * rs * g[tid + 256] + b[tid + 256]);
  orow[tid + 512] = f2bf((v2 - mu) * rs * g[tid + 512] + b[tid + 512]);
}

// ---- all six weight transposes (fp32 [R,C] -> bf16 [C,R]) + bias concat -----
__global__ __launch_bounds__(256) void transpose_all(
    const float* __restrict__ wq, const float* __restrict__ wk,
    const float* __restrict__ wv, const float* __restrict__ wo,
    const float* __restrict__ w1, const float* __restrict__ w2,
    const float* __restrict__ bq, const float* __restrict__ bk,
    const float* __restrict__ bv,
    unsigned short* __restrict__ WqkvT, unsigned short* __restrict__ WoT,
    unsigned short* __restrict__ W1T, unsigned short* __restrict__ W2T,
    float* __restrict__ bqkv) {
  __shared__ float t[32][33];
  const int z = blockIdx.z;
  const int bx = blockIdx.x, by = blockIdx.y;
  if (z == 6) {
    if (by == 0 && bx < 9) {
      int i = bx * 256 + threadIdx.x;
      if (i < 768) bqkv[i] = bq[i];
      else if (i < 1536) bqkv[i] = bk[i - 768];
      else if (i < 2304) bqkv[i] = bv[i - 1536];
    }
    return;
  }
  const float* src; unsigned short* dst; int R, C, r0, c0;
  if (z < 4) {
    if (bx >= 24) return;
    R = 768; C = 768; r0 = by*32; c0 = bx*32;
    src = (z == 0) ? wq : (z == 1) ? wk : (z == 2) ? wv : wo;
    dst = (z == 0) ? WqkvT : (z == 1) ? WqkvT + 768*768 : (z == 2) ? WqkvT + 2*768*768 : WoT;
  } else if (z == 4) {
    R = 768; C = 3072; r0 = by*32; c0 = bx*32; src = w1; dst = W1T;
  } else {
    R = 3072; C = 768; r0 = bx*32; c0 = by*32; src = w2; dst = W2T;
  }
  int tx = threadIdx.x & 31, ty = threadIdx.x >> 5;
#pragma unroll
  for (int l = 0; l < 4; l++)
    t[ty + l*8][tx] = src[(long)(r0 + ty + l*8) * C + c0 + tx];
  __syncthreads();
#pragma unroll
  for (int l = 0; l < 4; l++)
    dst[(long)(c0 + ty + l*8) * R + r0 + tx] = f2bf(t[tx][ty + l*8]);
}

// --------- vT: qkv v-part [b,s,h,d] -> vT[bh][d][s] (row stride VLD) ---------
__global__ __launch_bounds__(256) void transpose_v(
    const unsigned short* __restrict__ qkv, unsigned short* __restrict__ vT) {
  __shared__ unsigned short t[32][33];
  int bhi = blockIdx.z;
  int b = bhi / HEADS, h = bhi % HEADS;
  int s0 = blockIdx.x * 32, d0 = blockIdx.y * 32;
  int tx = threadIdx.x & 31, ty = threadIdx.x >> 5;
  const unsigned short* base = qkv + ((long)b * SEQ) * (3*EMB) + 2*EMB + h*DKH;
#pragma unroll
  for (int l = 0; l < 4; l++) {
    int s = s0 + ty + l*8;
    t[ty + l*8][tx] = (s < SEQ) ? base[(long)s * (3*EMB) + d0 + tx] : (unsigned short)0;
  }
  __syncthreads();
  unsigned short* ob = vT + ((long)bhi * DKH) * VLD;
#pragma unroll
  for (int l = 0; l < 4; l++) {
    int d = d0 + ty + l*8;
    int s = s0 + tx;
    if (s < SEQ) ob[(long)d * VLD + s] = t[tx][ty + l*8];
  }
}

// ---- depth-3 pipelined GEMM: C[M,N] = A[M,K] @ Bt[N,K]^T --------------------
// 3-stage LDS ring; stage k+2 issued while computing k; vmcnt(2L) means only
// tile k's loads must have retired (two iterations of slack to cover L2/L3
// latency). Raw s_barrier (NOT __syncthreads — its lowering drains vmcnt(0)).
// Serpentine column order keeps boundary B tiles L2-hot across bands.
template<bool BIAS, bool RESID, bool GELU_, bool OF32, int BM, int BN>
__global__ __launch_bounds__(256) void gemm_pipe(
    const unsigned short* __restrict__ A,
    const unsigned short* __restrict__ Bt,
    const float* __restrict__ bias,
    const float* __restrict__ resid,
    float* __restrict__ outf,
    unsigned short* __restrict__ outb,
    int M, int N, int K, int lda, int ldb, int ldc,
    int CX, int CY) {
  constexpr int MT = BM / 32, NT = BN / 32;
  constexpr int MA = BM / 64, NA = BN / 64;
  constexpr int L = MA + NA;
  __shared__ unsigned short As[3][BM * 32];
  __shared__ unsigned short Bs[3][BN * 32];

  const int bid = blockIdx.x;
  const int xcd = bid & 7;
  const int sidx = bid >> 3;
  const int bg = sidx / CX;
  int colt = sidx % CX;
  if (bg & 1) colt = CX - 1 - colt;      // serpentine: reuse boundary B tiles
  const int band = bg * 8 + xcd;
  if (band >= CY) return;
  const int m0 = band * BM, n0 = colt * BN;

  const int tid = threadIdx.x;
  const int wave = tid >> 6, lane = tid & 63;
  const int wm = (wave >> 1) * (BM / 2), wn = (wave & 1) * (BN / 2);
  const int lm = lane & 15, q = lane >> 4;
  const int qs = ((q ^ ((lm >> 1) & 3)) * 8);

  const int srow = tid >> 2;
  const int scol = (((tid & 3) ^ ((tid >> 3) & 3)) * 8);
  int gmA[MA];
#pragma unroll
  for (int t = 0; t < MA; t++) {
    gmA[t] = m0 + srow + t * 64;
    if (gmA[t] > M - 1) gmA[t] = M - 1;
  }
  int gnB[NA];
#pragma unroll
  for (int t = 0; t < NA; t++) gnB[t] = n0 + srow + t * 64;

  auto stage = [&](int kIter, int buf) {
    const int k0 = kIter << 5;
#pragma unroll
    for (int t = 0; t < MA; t++)
      gld_lds16(A + (long)gmA[t] * lda + k0 + scol, &As[buf][8*tid + t*2048]);
#pragma unroll
    for (int t = 0; t < NA; t++)
      gld_lds16(Bt + (long)gnB[t] * ldb + k0 + scol, &Bs[buf][8*tid + t*2048]);
  };

  f32x4 acc[MT][NT];
#pragma unroll
  for (int i = 0; i < MT; i++)
#pragma unroll
    for (int j = 0; j < NT; j++) acc[i][j] = (f32x4){0,0,0,0};

  const int iters = K >> 5;
  stage(0, 0);
  stage(1, 1);
  int cur = 0;
  for (int k = 0; k < iters; k++) {
    if (k + 2 < iters) {
      int nb = cur + 2; if (nb >= 3) nb -= 3;
      stage(k + 2, nb);
      waitcnt_vm<2 * L>();     // only tile k's loads must be done
    } else if (k + 1 < iters) {
      waitcnt_vm<L>();
    } else {
      waitcnt_vm<0>();
    }
    asm volatile("s_barrier" ::: "memory");

    short8 af[MT], bf[NT];
#pragma unroll
    for (int i = 0; i < MT; i++) af[i] = *(const short8*)&As[cur][(wm + i*16 + lm) * 32 + qs];
#pragma unroll
    for (int j = 0; j < NT; j++) bf[j] = *(const short8*)&Bs[cur][(wn + j*16 + lm) * 32 + qs];
#pragma unroll
    for (int i = 0; i < MT; i++)
#pragma unroll
      for (int j = 0; j < NT; j++)
        acc[i][j] = __builtin_amdgcn_mfma_f32_16x16x32_bf16(af[i], bf[j], acc[i][j], 0, 0, 0);

    asm volatile("s_waitcnt lgkmcnt(0)" ::: "memory");
    asm volatile("s_barrier" ::: "memory");
    cur++; if (cur >= 3) cur = 0;
  }

#pragma unroll
  for (int i = 0; i < MT; i++) {
#pragma unroll
    for (int j = 0; j < NT; j++) {
      int col = n0 + wn + j*16 + lm;
      float bv = BIAS ? bias[col] : 0.0f;
#pragma unroll
      for (int r = 0; r < 4; r++) {
        int row = m0 + wm + i*16 + q*4 + r;
        if (row >= M) continue;
        float v = acc[i][j][r] + bv;
        if (RESID) v += resid[(long)row * ldc + col];
        if (GELU_) v = gelu_f(v);
        long o = (long)row * ldc + col;
        if (OF32)   outf[o] = v;
        else        outb[o] = f2bf(v);
      }
    }
  }
}

// ------- flash attention v2: fixed-shift softmax, Q128, swizzled LDS ---------
#define QT 128
__global__ __launch_bounds__(256) void flash_attn2(
    const unsigned short* __restrict__ qkv,   // [MTOK][2304], q|k|v
    const unsigned short* __restrict__ vT,    // [bh][64][VLD]
    unsigned short* __restrict__ ctx) {       // [MTOK][768]
  __shared__ unsigned short Qs[QT * 64];
  __shared__ unsigned short Ks[64 * 64];
  __shared__ unsigned short Vs[64 * 64];
  __shared__ unsigned short Ps[QT * 64];

  const int q0 = blockIdx.x * QT;
  const int bh = blockIdx.y;
  const int b = bh / HEADS, h = bh % HEADS;
  const int tid = threadIdx.x;
  const int wave = tid >> 6, lane = tid & 63;
  const int lm = lane & 15, q = lane >> 4;
  const int xlm = (lm >> 1) & 3;

  const int sr = tid >> 3;
  const int gcol = ((tid & 7) ^ ((sr >> 1) & 3)) * 8;

#pragma unroll
  for (int it = 0; it < 4; it++) {
    int r = sr + it*32;
    int s = q0 + r; if (s > SEQ - 1) s = SEQ - 1;
    gld_lds16(qkv + ((long)(b*SEQ + s))*(3*EMB) + h*DKH + gcol, &Qs[8*tid + it*2048]);
  }
  waitcnt_vm<0>();
  __syncthreads();

  short8 qf[2][2];
#pragma unroll
  for (int rt = 0; rt < 2; rt++)
#pragma unroll
    for (int kk = 0; kk < 2; kk++)
      qf[rt][kk] = *(const short8*)&Qs[(wave*32 + rt*16 + lm)*64 + ((kk*4 + q) ^ xlm)*8];

  f32x4 oacc[2][4];
  float lsum[2][4];
#pragma unroll
  for (int rt = 0; rt < 2; rt++)
#pragma unroll
    for (int j = 0; j < 4; j++) oacc[rt][j] = (f32x4){0,0,0,0};
#pragma unroll
  for (int rt = 0; rt < 2; rt++)
#pragma unroll
    for (int r = 0; r < 4; r++) lsum[rt][r] = 0.f;

  for (int kt = 0; kt < 10; kt++) {
    __syncthreads();
#pragma unroll
    for (int it = 0; it < 2; it++) {
      int r = sr + it*32;
      int s = kt*64 + r; if (s > SEQ - 1) s = SEQ - 1;
      gld_lds16(qkv + ((long)(b*SEQ + s))*(3*EMB) + EMB + h*DKH + gcol, &Ks[8*tid + it*2048]);
      gld_lds16(vT + ((long)bh*DKH + r)*VLD + (long)kt*64 + gcol, &Vs[8*tid + it*2048]);
    }
    waitcnt_vm<0>();
    __syncthreads();

    f32x4 sacc[2][4];
#pragma unroll
    for (int t = 0; t < 4; t++) {
      short8 kf0 = *(const short8*)&Ks[(t*16 + lm)*64 + ((0 + q) ^ xlm)*8];
      short8 kf1 = *(const short8*)&Ks[(t*16 + lm)*64 + ((4 + q) ^ xlm)*8];
      bool dead = (kt*64 + t*16 + lm) >= SEQ;
#pragma unroll
      for (int rt = 0; rt < 2; rt++) {
        f32x4 s0 = __builtin_amdgcn_mfma_f32_16x16x32_bf16(qf[rt][0], kf0, (f32x4){0,0,0,0}, 0, 0, 0);
        s0 = __builtin_amdgcn_mfma_f32_16x16x32_bf16(qf[rt][1], kf1, s0, 0, 0, 0);
        sacc[rt][t] = dead ? (f32x4){-1e30f,-1e30f,-1e30f,-1e30f} : s0;
      }
    }

#pragma unroll
    for (int rt = 0; rt < 2; rt++)
#pragma unroll
      for (int t = 0; t < 4; t++)
#pragma unroll
        for (int r = 0; r < 4; r++) {
          float p = __expf(sacc[rt][t][r] - 8.0f);
          lsum[rt][r] += p;
          int row = wave*32 + rt*16 + q*4 + r;
          int g = (t*2 + (lm >> 3)) ^ ((q*2 + (r >> 1)) & 3);
          Ps[row*64 + g*8 + (lm & 7)] = f2bf(p);
        }

#pragma unroll
    for (int kk = 0; kk < 2; kk++) {
      short8 vf[4];
#pragma unroll
      for (int j = 0; j < 4; j++)
        vf[j] = *(const short8*)&Vs[(j*16 + lm)*64 + ((kk*4 + q) ^ xlm)*8];
#pragma unroll
      for (int rt = 0; rt < 2; rt++) {
        short8 pf = *(const short8*)&Ps[(wave*32 + rt*16 + lm)*64 + ((kk*4 + q) ^ xlm)*8];
#pragma unroll
        for (int j = 0; j < 4; j++)
          oacc[rt][j] = __builtin_amdgcn_mfma_f32_16x16x32_bf16(pf, vf[j], oacc[rt][j], 0, 0, 0);
      }
    }
  }

#pragma unroll
  for (int rt = 0; rt < 2; rt++)
#pragma unroll
    for (int r = 0; r < 4; r++) {
      float l = lsum[rt][r];
      l += __shfl_xor(l, 1, 64);
      l += __shfl_xor(l, 2, 64);
      l += __shfl_xor(l, 4, 64);
      l += __shfl_xor(l, 8, 64);
      lsum[rt][r] = 1.0f / l;
    }

#pragma unroll
  for (int rt = 0; rt < 2; rt++)
#pragma unroll
    for (int j = 0; j < 4; j++)
#pragma unroll
      for (int r = 0; r < 4; r++) {
        int row = q0 + wave*32 + rt*16 + q*4 + r;
        if (row < SEQ)
          ctx[((long)(b*SEQ + row))*EMB + h*DKH + j*16 + lm] =
              f2bf(oacc[rt][j][r] * lsum[rt][r]);
      }
}

extern "C" void kernel_launch(void* const* d_in, const int* in_sizes, int n_in,
                              void* d_out, int out_size, void* d_ws, size_t ws_size,
                              hipStream_t stream) {
  const float* x     = (const float*)d_in[0];
  const float* wq    = (const float*)d_in[1];
  const float* bq    = (const float*)d_in[2];
  const float* wk    = (const float*)d_in[3];
  const float* bk    = (const float*)d_in[4];
  const float* wv    = (const float*)d_in[5];
  const float* bv    = (const float*)d_in[6];
  const float* wo    = (const float*)d_in[7];
  const float* bo    = (const float*)d_in[8];
  const float* w1    = (const float*)d_in[9];
  const float* bf1   = (const float*)d_in[10];
  const float* w2    = (const float*)d_in[11];
  const float* bf2   = (const float*)d_in[12];
  const float* ln1g  = (const float*)d_in[13];
  const float* ln1b  = (const float*)d_in[14];
  const float* ln2g  = (const float*)d_in[15];
  const float* ln2b  = (const float*)d_in[16];
  float* out = (float*)d_out;

  char* w = (char*)d_ws;
  size_t off = 0;
  auto alloc = [&](size_t bytes) -> void* {
    void* p = w + off;
    off = (off + bytes + 255) & ~(size_t)255;
    return p;
  };
  unsigned short* WqkvT = (unsigned short*)alloc((size_t)3 * 768 * 768 * 2);
  unsigned short* WoT   = (unsigned short*)alloc((size_t)768 * 768 * 2);
  unsigned short* W1T   = (unsigned short*)alloc((size_t)3072 * 768 * 2);
  unsigned short* W2T   = (unsigned short*)alloc((size_t)768 * 3072 * 2);
  float*          bqkv  = (float*)alloc(2304 * 4);
  unsigned short* hbuf  = (unsigned short*)alloc((size_t)MTOK * EMB * 2);
  unsigned short* qkv   = (unsigned short*)alloc((size_t)MTOK * 3 * EMB * 2);
  unsigned short* vT    = (unsigned short*)alloc((size_t)BHN * DKH * VLD * 2);
  float*          x1    = (float*)alloc((size_t)MTOK * EMB * 4);
  unsigned short* g     = (unsigned short*)alloc((size_t)MTOK * DFF * 2);
  (void)ws_size; (void)in_sizes; (void)n_in; (void)out_size;

  dim3 blk(256);
  const int B128 = ((73 + 7) / 8) * 8;    // 80 padded bands of 128 rows

  transpose_all<<<dim3(96, 24, 7), blk, 0, stream>>>(
      wq, wk, wv, wo, w1, w2, bq, bk, bv, WqkvT, WoT, W1T, W2T, bqkv);

  ln_kernel<<<dim3(MTOK), blk, 0, stream>>>(x, ln1g, ln1b, hbuf);

  // QKV: [9232,768] @ [768,2304], 128x128 depth-3, CX=18
  gemm_pipe<true, false, false, false, 128, 128><<<dim3(18 * B128), blk, 0, stream>>>(
      hbuf, WqkvT, bqkv, nullptr, nullptr, qkv,
      MTOK, 3*EMB, EMB, EMB, EMB, 3*EMB, 18, 73);

  transpose_v<<<dim3(19, 2, BHN), blk, 0, stream>>>(qkv, vT);

  // fused attention v2 -> ctx (hbuf); 5 q-tiles of 128, 192 bh
  flash_attn2<<<dim3(5, BHN), blk, 0, stream>>>(qkv, vT, hbuf);

  // O-proj + residual -> x1 (fp32); 128x64 depth-3, CX=12
  gemm_pipe<true, true, false, true, 128, 64><<<dim3(12 * B128), blk, 0, stream>>>(
      hbuf, WoT, bo, x, x1, nullptr,
      MTOK, EMB, EMB, EMB, EMB, EMB, 12, 73);

  ln_kernel<<<dim3(MTOK), blk, 0, stream>>>(x1, ln2g, ln2b, hbuf);

  // FFN1 + bias + fast GELU -> g (bf16); 128x128 depth-3, CX=24
  gemm_pipe<true, false, true, false, 128, 128><<<dim3(24 * B128), blk, 0, stream>>>(
      hbuf, W1T, bf1, nullptr, nullptr, g,
      MTOK, DFF, EMB, EMB, EMB, DFF, 24, 73);

  // FFN2 + bias + residual -> out (fp32); 128x64 depth-3, CX=12
  gemm_pipe<true, true, false, true, 128, 64><<<dim3(12 * B128), blk, 0, stream>>>(
      g, W2T, bf2, x1, out, nullptr,
      MTOK, EMB, DFF, DFF, DFF, EMB, 12, 73);
}